// Round 3
// baseline (377.869 us; speedup 1.0000x reference)
//
#include <hip/hip_runtime.h>
#include <math.h>

// Problem constants (from reference): N slices of D x D matrices.
#define NSL 262144
#define D 16

// r_matrix layout is [D, D, N] -> element (i,j) of slice n at (i*D+j)*N + n.
// One thread per slice: every load of a fixed (i,j) is perfectly coalesced
// across the wave (64 consecutive n -> one 256B aligned transaction).

__global__ void zero_ws_kernel(double* ws) { ws[0] = 0.0; }

__global__ void finalize_kernel(const double* __restrict__ ws,
                                float* __restrict__ out) {
    out[0] = (float)ws[0];
}

// Doolittle row-streaming LU (no pivoting; matrices are I + 0.1*noise,
// well-conditioned). Keeps only the upper triangle live -> ~190 VGPRs,
// allowing 2 waves/SIMD with __launch_bounds__(256, 2).
__global__ __launch_bounds__(256, 2) void loss_kernel(
    const float* __restrict__ gamma,
    const float* __restrict__ exp_cpv,
    const float* __restrict__ rmat,
    double* __restrict__ ws) {
    const int n = blockIdx.x * blockDim.x + threadIdx.x;

    // diff = gamma[n,:] - exp_cpv[n,:]  (contiguous 64B per thread, float4 x4)
    float diff[D];
    {
        const float4* g4 = reinterpret_cast<const float4*>(gamma + (size_t)n * D);
        const float4* e4 = reinterpret_cast<const float4*>(exp_cpv + (size_t)n * D);
#pragma unroll
        for (int c = 0; c < 4; ++c) {
            float4 g = g4[c];
            float4 e = e4[c];
            diff[4 * c + 0] = g.x - e.x;
            diff[4 * c + 1] = g.y - e.y;
            diff[4 * c + 2] = g.z - e.z;
            diff[4 * c + 3] = g.w - e.w;
        }
    }

    const float* Rb = rmat + n;

    float U[D][D];   // only j > i entries stay live (upper triangle)
    float invd[D];   // 1 / u_kk
    float vsq = 0.0f;      // sum v_i^2 (matvec with ORIGINAL rows)
    float detprod = 1.0f;  // product of pivots

#pragma unroll
    for (int i = 0; i < D; ++i) {
        // Load original row i (each load coalesced across the wave) and
        // accumulate the matvec before elimination destroys it.
        float a[D];
        float vi = 0.0f;
#pragma unroll
        for (int j = 0; j < D; ++j) {
            a[j] = Rb[(size_t)(i * D + j) * NSL];
            vi += a[j] * diff[j];
        }
        vsq += vi * vi;

        // Fold row i against previously finalized U rows 0..i-1.
#pragma unroll
        for (int k = 0; k < i; ++k) {
            float m = a[k] * invd[k];
#pragma unroll
            for (int j = k + 1; j < D; ++j) a[j] -= m * U[k][j];
        }

        // Row i finalized: pivot is a[i].
        detprod *= a[i];
        invd[i] = 1.0f / a[i];
#pragma unroll
        for (int j = i + 1; j < D; ++j) U[i][j] = a[j];
    }

    const float l2 = sqrtf(vsq);
    const float logabs = logf(fabsf(detprod));
    double c = (double)l2 - 2.0 * (double)logabs;

    // Wave (64-lane) reduction.
#pragma unroll
    for (int off = 32; off > 0; off >>= 1) c += __shfl_down(c, off, 64);

    __shared__ double wsum[4];
    const int lane = threadIdx.x & 63;
    const int wv = threadIdx.x >> 6;
    if (lane == 0) wsum[wv] = c;
    __syncthreads();
    if (threadIdx.x == 0) {
        double s = (wsum[0] + wsum[1]) + (wsum[2] + wsum[3]);
        atomicAdd(ws, s);
    }
}

extern "C" void kernel_launch(void* const* d_in, const int* in_sizes, int n_in,
                              void* d_out, int out_size, void* d_ws, size_t ws_size,
                              hipStream_t stream) {
    const float* gamma = (const float*)d_in[0];
    const float* exp_cpv = (const float*)d_in[1];
    const float* rmat = (const float*)d_in[2];
    float* out = (float*)d_out;
    double* ws = (double*)d_ws;

    zero_ws_kernel<<<1, 1, 0, stream>>>(ws);
    loss_kernel<<<NSL / 256, 256, 0, stream>>>(gamma, exp_cpv, rmat, ws);
    finalize_kernel<<<1, 1, 0, stream>>>(ws, out);
}

// Round 5
// 377.616 us; speedup vs baseline: 1.0007x; 1.0007x over previous
//
#include <hip/hip_runtime.h>
#include <math.h>

// Problem constants (from reference): N slices of D x D matrices.
#define NSL 262144
#define D 16
#define NBLK (NSL / 256)  // 1024 partial sums

// r_matrix layout is [D, D, N] -> element (i,j) of slice n at (i*D+j)*N + n.
// One thread per slice: every load of a fixed (i,j) is perfectly coalesced
// across the wave (64 consecutive n -> one 256B aligned transaction).

// Final reduce: 1024 doubles -> one float. One block of 256 threads.
__global__ void finalize_kernel(const double* __restrict__ partial,
                                float* __restrict__ out) {
    const int t = threadIdx.x;
    double c = (partial[t] + partial[t + 256]) +
               (partial[t + 512] + partial[t + 768]);
#pragma unroll
    for (int off = 32; off > 0; off >>= 1) c += __shfl_down(c, off, 64);
    __shared__ double wsum[4];
    const int lane = t & 63, wv = t >> 6;
    if (lane == 0) wsum[wv] = c;
    __syncthreads();
    if (t == 0) out[0] = (float)((wsum[0] + wsum[1]) + (wsum[2] + wsum[3]));
}

// Doolittle row-streaming LU (no pivoting; matrices are I + 0.1*noise,
// well-conditioned -> absmax was 0.0 vs reference). Only the upper triangle
// stays live; explicit next-row prefetch guarantees the 16 loads of row i+1
// are in flight while row i is eliminated (~215 VGPRs, 2 waves/SIMD).
__global__ __launch_bounds__(256, 2) void loss_kernel(
    const float* __restrict__ gamma,
    const float* __restrict__ exp_cpv,
    const float* __restrict__ rmat,
    double* __restrict__ partial) {
    const int n = blockIdx.x * blockDim.x + threadIdx.x;

    // diff = gamma[n,:] - exp_cpv[n,:]  (contiguous 64B per thread, float4 x4)
    float diff[D];
    {
        const float4* g4 = reinterpret_cast<const float4*>(gamma + (size_t)n * D);
        const float4* e4 = reinterpret_cast<const float4*>(exp_cpv + (size_t)n * D);
#pragma unroll
        for (int c = 0; c < 4; ++c) {
            float4 g = g4[c];
            float4 e = e4[c];
            diff[4 * c + 0] = g.x - e.x;
            diff[4 * c + 1] = g.y - e.y;
            diff[4 * c + 2] = g.z - e.z;
            diff[4 * c + 3] = g.w - e.w;
        }
    }

    const float* Rb = rmat + n;

    float U[D][D];   // only j > i entries stay live (upper triangle)
    float invd[D];   // 1 / u_kk
    float vsq = 0.0f;      // sum v_i^2 (matvec with ORIGINAL rows)
    float detprod = 1.0f;  // product of pivots

    float a[D];      // current row (original values on entry to iteration i)
    float nxt[D];    // prefetched next row
#pragma unroll
    for (int j = 0; j < D; ++j) a[j] = Rb[(size_t)j * NSL];

#pragma unroll
    for (int i = 0; i < D; ++i) {
        // Issue next row's loads FIRST so they overlap the elimination math.
        if (i < D - 1) {
#pragma unroll
            for (int j = 0; j < D; ++j)
                nxt[j] = Rb[(size_t)((i + 1) * D + j) * NSL];
        }

        // Matvec with the ORIGINAL row before elimination destroys it.
        float vi = 0.0f;
#pragma unroll
        for (int j = 0; j < D; ++j) vi += a[j] * diff[j];
        vsq += vi * vi;

        // Fold row i against previously finalized U rows 0..i-1.
#pragma unroll
        for (int k = 0; k < i; ++k) {
            float m = a[k] * invd[k];
#pragma unroll
            for (int j = k + 1; j < D; ++j) a[j] -= m * U[k][j];
        }

        // Row i finalized: pivot is a[i].
        detprod *= a[i];
        invd[i] = 1.0f / a[i];
#pragma unroll
        for (int j = i + 1; j < D; ++j) U[i][j] = a[j];

        if (i < D - 1) {
#pragma unroll
            for (int j = 0; j < D; ++j) a[j] = nxt[j];
        }
    }

    const float l2 = sqrtf(vsq);
    const float logabs = logf(fabsf(detprod));
    double c = (double)l2 - 2.0 * (double)logabs;

    // Wave (64-lane) reduction, then one plain store per block (no atomic,
    // no ws zero-init needed: finalize reads exactly the written slots).
#pragma unroll
    for (int off = 32; off > 0; off >>= 1) c += __shfl_down(c, off, 64);

    __shared__ double wsum[4];
    const int lane = threadIdx.x & 63;
    const int wv = threadIdx.x >> 6;
    if (lane == 0) wsum[wv] = c;
    __syncthreads();
    if (threadIdx.x == 0) {
        partial[blockIdx.x] = (wsum[0] + wsum[1]) + (wsum[2] + wsum[3]);
    }
}

extern "C" void kernel_launch(void* const* d_in, const int* in_sizes, int n_in,
                              void* d_out, int out_size, void* d_ws, size_t ws_size,
                              hipStream_t stream) {
    const float* gamma = (const float*)d_in[0];
    const float* exp_cpv = (const float*)d_in[1];
    const float* rmat = (const float*)d_in[2];
    float* out = (float*)d_out;
    double* partial = (double*)d_ws;

    loss_kernel<<<NBLK, 256, 0, stream>>>(gamma, exp_cpv, rmat, partial);
    finalize_kernel<<<1, 256, 0, stream>>>(partial, out);
}